// Round 1
// baseline (875.378 us; speedup 1.0000x reference)
//
#include <hip/hip_runtime.h>
#include <math.h>

#define SB 1024
#define NS 64
#define BT 256
#define HID 64
#define HEAD 128
#define IN_DIM 42

__global__ __launch_bounds__(256, 2) void cam_weighter_kernel(
    const float* __restrict__ input_poses,   // (SB,NS,4,4)
    const float* __restrict__ target_poses,  // (SB,BT,4,4)
    const float* __restrict__ W1, const float* __restrict__ b1,  // (42,64),(64)
    const float* __restrict__ W2, const float* __restrict__ b2,  // (64,64),(64)
    const float* __restrict__ W3, const float* __restrict__ b3,  // (64,128),(128)
    float* __restrict__ out)                 // (SB,NS,BT)
{
    __shared__ float xk_lds[HEAD][NS];      // [d][k]  32 KiB
    __shared__ float yk_t[HID][NS];         // [j][k]  16 KiB (W3 @ xk, transposed)
    __shared__ float ck_lds[NS];            // b3 . xk

    const int s   = blockIdx.x;
    const int tid = threadIdx.x;

    float h2[HID];

    #pragma unroll 1
    for (int ph = 0; ph < 2; ++ph) {
        const bool active = (ph == 1) || (tid < NS);
        if (active) {
            const float* pose = ph ? &target_poses[(size_t)(s * BT + tid) * 16]
                                   : &input_poses [(size_t)(s * NS + tid) * 16];
            // dirs = pose[:3,2], locs = pose[:3,3] -> row r holds (dir_r, loc_r) at +r*4+2
            float dirs[3], locs[3];
            #pragma unroll
            for (int r = 0; r < 3; ++r) {
                float2 v = *reinterpret_cast<const float2*>(pose + r * 4 + 2);
                dirs[r] = v.x; locs[r] = v.y;
            }
            // positional encoding -> x[42]
            float x[IN_DIM];
            x[0] = locs[0]; x[1] = locs[1]; x[2] = locs[2];
            #pragma unroll
            for (int c = 0; c < 3; ++c) {
                float a  = 1.5f * locs[c];
                float sv = sinf(a), cv = cosf(a);
                #pragma unroll
                for (int i = 0; i < 6; ++i) {
                    x[3 + (2 * i) * 3 + c]     = sv;
                    x[3 + (2 * i + 1) * 3 + c] = cv;
                    float s2 = 2.f * sv * cv;          // sin(2a)
                    float c2 = cv * cv - sv * sv;      // cos(2a)
                    sv = s2; cv = c2;
                }
            }
            x[39] = dirs[0]; x[40] = dirs[1]; x[41] = dirs[2];

            // layer 1: 42 -> 64, relu   (W reads uniform -> s_load)
            float h1[HID];
            #pragma unroll
            for (int i = 0; i < HID; ++i) h1[i] = b1[i];
            #pragma unroll
            for (int j = 0; j < IN_DIM; ++j) {
                #pragma unroll
                for (int i = 0; i < HID; ++i)
                    h1[i] = fmaf(x[j], W1[j * HID + i], h1[i]);
            }
            #pragma unroll
            for (int i = 0; i < HID; ++i) h1[i] = fmaxf(h1[i], 0.f);

            // layer 2: 64 -> 64, relu
            #pragma unroll
            for (int i = 0; i < HID; ++i) h2[i] = b2[i];
            #pragma unroll
            for (int j = 0; j < HID; ++j) {
                #pragma unroll
                for (int i = 0; i < HID; ++i)
                    h2[i] = fmaf(h1[j], W2[j * HID + i], h2[i]);
            }
            #pragma unroll
            for (int i = 0; i < HID; ++i) h2[i] = fmaxf(h2[i], 0.f);
        }

        if (ph == 0) {
            // keys: layer 3 (64 -> 128) into LDS, lanes = keys
            if (active) {
                const int k = tid;
                for (int d = 0; d < HEAD; ++d) {       // d dynamic: W3 col uniform -> s_load
                    float acc = b3[d];
                    #pragma unroll
                    for (int j = 0; j < HID; ++j)
                        acc = fmaf(h2[j], W3[j * HEAD + d], acc);
                    xk_lds[d][k] = acc;
                }
            }
            __syncthreads();

            // yk[j][k] = sum_d W3[j][d] * xk[d][k];  ck[k] = b3 . xk[:,k]
            {
                const int k = tid & 63, jw = tid >> 6;   // jw wave-uniform
                float acc[16];
                #pragma unroll
                for (int jj = 0; jj < 16; ++jj) acc[jj] = 0.f;
                for (int d = 0; d < HEAD; ++d) {
                    float xv = xk_lds[d][k];
                    #pragma unroll
                    for (int jj = 0; jj < 16; ++jj)
                        acc[jj] = fmaf(xv, W3[(jw + 4 * jj) * HEAD + d], acc[jj]);
                }
                #pragma unroll
                for (int jj = 0; jj < 16; ++jj)
                    yk_t[jw + 4 * jj][k] = acc[jj];
                if (jw == 0) {
                    float c = 0.f;
                    for (int d = 0; d < HEAD; ++d)
                        c = fmaf(b3[d], xk_lds[d][k], c);
                    ck_lds[k] = c;
                }
            }
            __syncthreads();
        } else {
            // queries: scores vs all 64 keys, softmax, transposed store
            const int q = tid;
            float sc[NS];
            #pragma unroll
            for (int k = 0; k < NS; ++k) sc[k] = ck_lds[k];
            #pragma unroll
            for (int j = 0; j < HID; ++j) {
                const float hv = h2[j];
                #pragma unroll
                for (int k = 0; k < NS; ++k)
                    sc[k] = fmaf(hv, yk_t[j][k], sc[k]);   // broadcast LDS read
            }
            const float scale = 0.08838834764831845f;      // 1/sqrt(128)
            float m = -1e30f;
            #pragma unroll
            for (int k = 0; k < NS; ++k) { sc[k] *= scale; m = fmaxf(m, sc[k]); }
            float sum = 0.f;
            #pragma unroll
            for (int k = 0; k < NS; ++k) { sc[k] = __expf(sc[k] - m); sum += sc[k]; }
            const float inv = 1.f / sum;
            float* obase = out + (size_t)s * NS * BT + q;
            #pragma unroll
            for (int k = 0; k < NS; ++k)
                obase[(size_t)k * BT] = sc[k] * inv;       // lanes=q contiguous: coalesced
        }
    }
}

extern "C" void kernel_launch(void* const* d_in, const int* in_sizes, int n_in,
                              void* d_out, int out_size, void* d_ws, size_t ws_size,
                              hipStream_t stream) {
    const float* input_poses  = (const float*)d_in[0];
    const float* target_poses = (const float*)d_in[1];
    const float* W1 = (const float*)d_in[2];
    const float* b1 = (const float*)d_in[3];
    const float* W2 = (const float*)d_in[4];
    const float* b2 = (const float*)d_in[5];
    const float* W3 = (const float*)d_in[6];
    const float* b3 = (const float*)d_in[7];
    float* out = (float*)d_out;

    cam_weighter_kernel<<<dim3(SB), dim3(256), 0, stream>>>(
        input_poses, target_poses, W1, b1, W2, b2, W3, b3, out);
}

// Round 2
// 164.714 us; speedup vs baseline: 5.3145x; 5.3145x over previous
//
#include <hip/hip_runtime.h>
#include <math.h>

#define SB 1024
#define NS 64
#define BT 256
#define HID 64
#define IN_DIM 42

// 16 accumulators ACC[OFF..OFF+15] += V * WPTR[0..15]  (4x ds_read_b128)
#define FMA16(ACC, OFF, WPTR, V) do {                                   \
    const float4* _w4 = (const float4*)(WPTR);                          \
    float4 _a = _w4[0], _b = _w4[1], _c = _w4[2], _d = _w4[3];          \
    (ACC)[(OFF)+0]  = fmaf((V), _a.x, (ACC)[(OFF)+0]);                  \
    (ACC)[(OFF)+1]  = fmaf((V), _a.y, (ACC)[(OFF)+1]);                  \
    (ACC)[(OFF)+2]  = fmaf((V), _a.z, (ACC)[(OFF)+2]);                  \
    (ACC)[(OFF)+3]  = fmaf((V), _a.w, (ACC)[(OFF)+3]);                  \
    (ACC)[(OFF)+4]  = fmaf((V), _b.x, (ACC)[(OFF)+4]);                  \
    (ACC)[(OFF)+5]  = fmaf((V), _b.y, (ACC)[(OFF)+5]);                  \
    (ACC)[(OFF)+6]  = fmaf((V), _b.z, (ACC)[(OFF)+6]);                  \
    (ACC)[(OFF)+7]  = fmaf((V), _b.w, (ACC)[(OFF)+7]);                  \
    (ACC)[(OFF)+8]  = fmaf((V), _c.x, (ACC)[(OFF)+8]);                  \
    (ACC)[(OFF)+9]  = fmaf((V), _c.y, (ACC)[(OFF)+9]);                  \
    (ACC)[(OFF)+10] = fmaf((V), _c.z, (ACC)[(OFF)+10]);                 \
    (ACC)[(OFF)+11] = fmaf((V), _c.w, (ACC)[(OFF)+11]);                 \
    (ACC)[(OFF)+12] = fmaf((V), _d.x, (ACC)[(OFF)+12]);                 \
    (ACC)[(OFF)+13] = fmaf((V), _d.y, (ACC)[(OFF)+13]);                 \
    (ACC)[(OFF)+14] = fmaf((V), _d.z, (ACC)[(OFF)+14]);                 \
    (ACC)[(OFF)+15] = fmaf((V), _d.w, (ACC)[(OFF)+15]);                 \
} while (0)

#define FMA64(ACC, WPTR, V) do {                                        \
    FMA16(ACC, 0,  (WPTR) + 0,  V);                                     \
    FMA16(ACC, 16, (WPTR) + 16, V);                                     \
    FMA16(ACC, 32, (WPTR) + 32, V);                                     \
    FMA16(ACC, 48, (WPTR) + 48, V);                                     \
} while (0)

__device__ __forceinline__ void load_pose(const float* __restrict__ p,
                                          float& lx, float& ly, float& lz,
                                          float& dx, float& dy, float& dz) {
    // row r: p[r*4+2] = dir_r, p[r*4+3] = loc_r   (8B-aligned float2)
    float2 r0 = *(const float2*)(p + 2);
    float2 r1 = *(const float2*)(p + 6);
    float2 r2 = *(const float2*)(p + 10);
    dx = r0.x; lx = r0.y;
    dy = r1.x; ly = r1.y;
    dz = r2.x; lz = r2.y;
}

// Applies rowop(row, value) for the 42 PE features of (loc, dir):
// rows: [loc(3) | sin/cos interleaved 36 | dir(3)]; freqs 1.5*2^i via double-angle.
template <class F>
__device__ __forceinline__ void pe_apply(F&& rowop, float lx, float ly, float lz,
                                         float dx, float dy, float dz) {
    rowop(0, lx); rowop(1, ly); rowop(2, lz);
    #pragma unroll
    for (int c = 0; c < 3; ++c) {
        float lc = (c == 0) ? lx : ((c == 1) ? ly : lz);
        float sv, cv;
        __sincosf(1.5f * lc, &sv, &cv);
        #pragma unroll
        for (int i = 0; i < 6; ++i) {
            rowop(3 + 6 * i + c, sv);
            rowop(6 + 6 * i + c, cv);
            float ns = 2.f * sv * cv, nc = cv * cv - sv * sv;
            sv = ns; cv = nc;
        }
    }
    rowop(39, dx); rowop(40, dy); rowop(41, dz);
}

__global__ __launch_bounds__(256, 2) void cam_weighter_kernel(
    const float* __restrict__ input_poses,   // (SB,NS,4,4)
    const float* __restrict__ target_poses,  // (SB,BT,4,4)
    const float* __restrict__ W1, const float* __restrict__ b1,
    const float* __restrict__ W2, const float* __restrict__ b2,
    const float* __restrict__ W3, const float* __restrict__ b3,
    float* __restrict__ out)                 // (SB,NS,BT)
{
    __shared__ __align__(16) float W1l[IN_DIM * HID];  // 10.5 KB
    __shared__ __align__(16) float W2l[HID * HID];     // 16 KB
    __shared__ __align__(16) float Gl[HID * HID];      // 16 KB  G = W3 W3^T
    __shared__ __align__(16) float U[128 * 64];        // 32 KB  W3t -> h1|h2 -> zk|h2
    __shared__ __align__(16) float b1l[HID], b2l[HID], b3l[128], gl_s[HID], ckl[NS];

    const int tid = threadIdx.x;
    const int s   = blockIdx.x;
    const int k    = tid & 63;        // lane  (keys / G-row)
    const int part = tid >> 6;        // wave index (uniform)
    const int i0   = part << 4;

    // ---------- stage weights to LDS ----------
    for (int i = tid; i < IN_DIM * HID / 4; i += 256)
        ((float4*)W1l)[i] = ((const float4*)W1)[i];
    for (int i = tid; i < HID * HID / 4; i += 256)
        ((float4*)W2l)[i] = ((const float4*)W2)[i];
    for (int i = tid; i < HID * 128 / 4; i += 256) {   // W3 transposed: U[d*64+j]=W3[j*128+d]
        float4 v = ((const float4*)W3)[i];
        int j = i >> 5, d0 = (4 * i) & 127;
        U[(d0 + 0) * 64 + j] = v.x;
        U[(d0 + 1) * 64 + j] = v.y;
        U[(d0 + 2) * 64 + j] = v.z;
        U[(d0 + 3) * 64 + j] = v.w;
    }
    if (tid < 16)       ((float4*)b1l)[tid]      = ((const float4*)b1)[tid];
    else if (tid < 32)  ((float4*)b2l)[tid - 16] = ((const float4*)b2)[tid - 16];
    else if (tid < 64)  ((float4*)b3l)[tid - 32] = ((const float4*)b3)[tid - 32];
    __syncthreads();

    // ---------- G = W3 W3^T (64x64), g = W3 b3 ----------
    {
        float gacc[16];
        #pragma unroll
        for (int t = 0; t < 16; ++t) gacc[t] = 0.f;
        for (int d = 0; d < 128; ++d) {
            float wa = U[d * 64 + k];                 // lane-contiguous
            FMA16(gacc, 0, &U[d * 64 + i0], wa);      // broadcast
        }
        #pragma unroll
        for (int t = 0; t < 16; ++t) Gl[(i0 + t) * 64 + k] = gacc[t];  // symmetric store
        if (tid < 64) {
            float g = 0.f;
            for (int d = 0; d < 128; ++d) g = fmaf(U[d * 64 + tid], b3l[d], g);
            gl_s[tid] = g;
        }
    }
    __syncthreads();

    // ---------- keys: layer1 (42->64), quarter outputs per thread ----------
    {
        float lx, ly, lz, dx, dy, dz;
        load_pose(&input_poses[((size_t)s * NS + k) * 16], lx, ly, lz, dx, dy, dz);
        float h[16];
        #pragma unroll
        for (int t = 0; t < 16; ++t) h[t] = b1l[i0 + t];
        pe_apply([&](int row, float v) { FMA16(h, 0, &W1l[row * 64 + i0], v); },
                 lx, ly, lz, dx, dy, dz);
        #pragma unroll
        for (int t = 0; t < 16; ++t) U[(i0 + t) * 64 + k] = fmaxf(h[t], 0.f);  // h1[i][k]
    }
    __syncthreads();

    // ---------- keys: layer2 (64->64) ----------
    {
        float a2[16];
        #pragma unroll
        for (int t = 0; t < 16; ++t) a2[t] = b2l[i0 + t];
        for (int j = 0; j < HID; ++j) {
            float hv = U[j * 64 + k];                 // lane-contiguous
            FMA16(a2, 0, &W2l[j * 64 + i0], hv);      // broadcast
        }
        #pragma unroll
        for (int t = 0; t < 16; ++t) U[4096 + (i0 + t) * 64 + k] = fmaxf(a2[t], 0.f); // h2[i][k]
    }
    __syncthreads();

    // ---------- keys: zk = G h2_k, ck = g . h2_k ----------
    {
        float z[16];
        #pragma unroll
        for (int t = 0; t < 16; ++t) z[t] = 0.f;
        float cacc = 0.f;
        for (int jp = 0; jp < HID; ++jp) {
            float hv = U[4096 + jp * 64 + k];
            FMA16(z, 0, &Gl[jp * 64 + i0], hv);
            cacc = fmaf(hv, gl_s[jp], cacc);
        }
        #pragma unroll
        for (int t = 0; t < 16; ++t) U[(i0 + t) * 64 + k] = z[t];  // zk[j][k] over h1
        if (part == 0) ckl[k] = cacc;
    }
    __syncthreads();

    // ---------- queries: full MLP + scores + softmax ----------
    {
        float lx, ly, lz, dx, dy, dz;
        load_pose(&target_poses[((size_t)s * BT + tid) * 16], lx, ly, lz, dx, dy, dz);

        float h1[HID];
        #pragma unroll
        for (int t = 0; t < 16; ++t) {
            float4 b = ((const float4*)b1l)[t];
            h1[4*t] = b.x; h1[4*t+1] = b.y; h1[4*t+2] = b.z; h1[4*t+3] = b.w;
        }
        pe_apply([&](int row, float v) { FMA64(h1, &W1l[row * 64], v); },
                 lx, ly, lz, dx, dy, dz);
        #pragma unroll
        for (int i = 0; i < HID; ++i) h1[i] = fmaxf(h1[i], 0.f);

        float h2[HID];
        #pragma unroll
        for (int t = 0; t < 16; ++t) {
            float4 b = ((const float4*)b2l)[t];
            h2[4*t] = b.x; h2[4*t+1] = b.y; h2[4*t+2] = b.z; h2[4*t+3] = b.w;
        }
        #pragma unroll
        for (int j = 0; j < HID; ++j) FMA64(h2, &W2l[j * 64], h1[j]);
        #pragma unroll
        for (int i = 0; i < HID; ++i) h2[i] = fmaxf(h2[i], 0.f);

        float sc[NS];
        #pragma unroll
        for (int t = 0; t < 16; ++t) {
            float4 c = ((const float4*)ckl)[t];
            sc[4*t] = c.x; sc[4*t+1] = c.y; sc[4*t+2] = c.z; sc[4*t+3] = c.w;
        }
        #pragma unroll
        for (int j = 0; j < HID; ++j) FMA64(sc, &U[j * 64], h2[j]);

        // softmax over 64 (scale folded into exp; dropped terms are per-q constants)
        const float scale = 0.08838834764831845f;   // 1/sqrt(128)
        float m0 = sc[0], m1 = sc[1];
        #pragma unroll
        for (int kk = 2; kk < NS; kk += 2) { m0 = fmaxf(m0, sc[kk]); m1 = fmaxf(m1, sc[kk+1]); }
        const float m = fmaxf(m0, m1);
        float s0 = 0.f, s1 = 0.f;
        #pragma unroll
        for (int kk = 0; kk < NS; kk += 2) {
            sc[kk]   = __expf((sc[kk]   - m) * scale);
            sc[kk+1] = __expf((sc[kk+1] - m) * scale);
            s0 += sc[kk]; s1 += sc[kk+1];
        }
        const float inv = 1.f / (s0 + s1);
        float* obase = out + (size_t)s * NS * BT + tid;
        #pragma unroll
        for (int kk = 0; kk < NS; ++kk)
            obase[(size_t)kk * BT] = sc[kk] * inv;   // lanes=q contiguous
    }
}

extern "C" void kernel_launch(void* const* d_in, const int* in_sizes, int n_in,
                              void* d_out, int out_size, void* d_ws, size_t ws_size,
                              hipStream_t stream) {
    const float* input_poses  = (const float*)d_in[0];
    const float* target_poses = (const float*)d_in[1];
    const float* W1 = (const float*)d_in[2];
    const float* b1 = (const float*)d_in[3];
    const float* W2 = (const float*)d_in[4];
    const float* b2 = (const float*)d_in[5];
    const float* W3 = (const float*)d_in[6];
    const float* b3 = (const float*)d_in[7];
    float* out = (float*)d_out;

    cam_weighter_kernel<<<dim3(SB), dim3(256), 0, stream>>>(
        input_poses, target_poses, W1, b1, W2, b2, W3, b3, out);
}